// Round 7
// baseline (292.429 us; speedup 1.0000x reference)
//
#include <hip/hip_runtime.h>

#define B_ 4
#define N_ 8192
#define DIN 64
#define HDIM 64
#define DOUT 128
#define KNN 16
#define QPB 16               // queries per block
#define QPW 4                // queries per wave (key occupancy knob)
#define NTHR 256             // 4 waves
#define BUFS 64              // survivor-buffer slots per query
#define BLOCKS_PER_B (N_ / QPB)  // 512 -> grid 2048

__device__ __forceinline__ int mbcnt64(unsigned long long m) {
  return __builtin_amdgcn_mbcnt_hi((unsigned)(m >> 32),
         __builtin_amdgcn_mbcnt_lo((unsigned)m, 0));
}
// monotone float->uint map (total order, negatives below positives)
__device__ __forceinline__ unsigned mapkey(float d) {
  unsigned u = __float_as_uint(d);
  return (d < 0.0f) ? ~u : (u | 0x80000000u);
}
__device__ __forceinline__ float rf(float x) {  // force wave-uniform into SGPR
  return __int_as_float(__builtin_amdgcn_readfirstlane(__float_as_int(x)));
}

// Wave-cooperative exact 16 smallest by (key, idx) among cnt slots (cnt<=64).
// fout==null: compact kept 16 to slots 0..15, return kth distance (unmapped).
// fout!=null: write kept idx to fout[rank*QPB].
__device__ __forceinline__
float select16(unsigned* skQ, unsigned short* siQ, int cnt, unsigned short* fout) {
  const int l = threadIdx.x & 63;
  unsigned k = 0xFFFFFFFFu;
  unsigned mi = 0xFFFFu;
  if (l < cnt) { k = skQ[l]; mi = siQ[l]; }
  // radix-select 16th smallest key (bitwise, MSB->LSB)
  unsigned p = 0; int r = KNN;
  for (int bit = 31; bit >= 0; bit--) {
    unsigned long long ml = __ballot((int)(((k ^ p) >> bit) == 0u));
    int c0 = __popcll(ml);
    if (r > c0) { p |= (1u << bit); r -= c0; }
  }
  bool isLT = (k < p), isTie = (k == p);
  int tieC = __popcll(__ballot((int)isTie));
  bool keepT = isTie;
  if (tieC != r) {  // break ties at the kth value by smallest index
    unsigned mk = isTie ? mi : 0xFFFFFFFFu;
    unsigned p2 = 0; int r2 = r;
    for (int bit = 15; bit >= 0; bit--) {
      unsigned long long ml = __ballot((int)(((mk ^ p2) >> bit) == 0u));
      int c0 = __popcll(ml);
      if (r2 > c0) { p2 |= (1u << bit); r2 -= c0; }
    }
    keepT = isTie && (mi <= p2);
  }
  bool keep = isLT || keepT;
  unsigned long long km = __ballot((int)keep);
  int rank = mbcnt64(km);
  if (fout) {
    if (keep) fout[rank * QPB] = (unsigned short)mi;
  } else {
    if (keep) { skQ[rank] = k; siQ[rank] = (unsigned short)mi; }
  }
  unsigned fb = (p & 0x80000000u) ? (p & 0x7FFFFFFFu) : ~p;  // unmap
  return __uint_as_float(fb);
}

// ---------------- fully fused kernel ----------------
// Phase 0: compose 3 affine layers -> prmL (A,B,C,D per channel)
// Phase 1: transposed kNN scan, wave owns 4 queries (state in SGPRs);
//          lanes = candidates, depth-2 prefetch; survivors -> 64-slot LDS
//          buffer per query; exact radix-select compaction sets tau.
// Phase 2: final selection -> fidx; gather; fe = affine+maxpool (via LDS);
//          shortcut GEMM reading ws from L1; store.
__global__ __launch_bounds__(NTHR, 8) void k_lfa(
    const float* __restrict__ xyz, const float* __restrict__ feature,
    const float* __restrict__ w1, const float* __restrict__ b1,
    const float* __restrict__ w2, const float* __restrict__ b2,
    const float* __restrict__ w3, const float* __restrict__ b3,
    const float* __restrict__ wsM, const float* __restrict__ bs,
    float* __restrict__ out) {
  const int blk = blockIdx.x;
  const int b  = blk >> 9;              // blk / 512
  const int n0 = (blk & 511) << 4;      // 16 queries per block
  const int t = threadIdx.x;
  const int lane = t & 63;
  const int j = __builtin_amdgcn_readfirstlane(t >> 6);  // wave 0..3
  const float* xb = xyz + (size_t)b * 3 * N_;
  const float INF = __uint_as_float(0x7f800000u);

  // 12.5 KB pool, time-multiplexed:
  //  phase0: M2[64][10] @0, bb @2560
  //  scan:   skey[16][64] u32 @0 (4K), sidx[16][64] u16 @4096 (2K),
  //          fidx[16][16] u16 @6144 (512B), prmL[128] f4 @6656 (2K)
  //  epi:    neigh rows [64][16] f32 @0 (4K), feFe[64][16] f32 @8704 (4K),
  //          feL[64][16] f32 @0 (reuses neigh after fe)
  __shared__ alignas(16) unsigned char poolRaw[12800];
  unsigned* skey = (unsigned*)poolRaw;
  unsigned short* sidx = (unsigned short*)(poolRaw + 4096);
  unsigned short* fidx = (unsigned short*)(poolRaw + 6144);
  float4* prmL = (float4*)(poolRaw + 6656);

  // ---- phase 0: affine composition (wave 0 only) ----
  {
    float* M2 = (float*)poolRaw;             // [64][10]
    float* bbv = (float*)(poolRaw + 2560);   // [64]
    if (t < HDIM) {
      float r[10];
#pragma unroll
      for (int c = 0; c < 10; c++) r[c] = 0.f;
      float s = b2[t];
      for (int ll = 0; ll < HDIM; ll++) {
        float w = w2[t * HDIM + ll];
#pragma unroll
        for (int c = 0; c < 10; c++) r[c] = fmaf(w, w1[ll * 10 + c], r[c]);
        s = fmaf(w, b1[ll], s);
      }
#pragma unroll
      for (int c = 0; c < 10; c++) M2[t * 10 + c] = r[c];
      bbv[t] = s;
    }
    __syncthreads();
    float4 pv0, pv1;
    if (t < HDIM) {
      float r3[10];
#pragma unroll
      for (int c = 0; c < 10; c++) r3[c] = 0.f;
      float bc = b3[t];
      for (int ll = 0; ll < HDIM; ll++) {
        float w = w3[t * HDIM + ll];
#pragma unroll
        for (int c = 0; c < 10; c++) r3[c] = fmaf(w, M2[ll * 10 + c], r3[c]);
        bc = fmaf(w, bbv[ll], bc);
      }
      pv0 = make_float4(r3[0] - r3[6], r3[1] - r3[7], r3[2] - r3[8], bc);
      pv1 = make_float4(r3[3] + r3[6], r3[4] + r3[7], r3[5] + r3[8], r3[9]);
    }
    __syncthreads();  // M2/bb region about to be reused by skey
    if (t < HDIM) { prmL[t] = pv0; prmL[64 + t] = pv1; }
  }

  // ---- phase 1: scan (wave owns queries n0 + j*4 .. +3) ----
  float qX[QPW], qY[QPW], qZ[QPW], qS[QPW];  // wave-uniform -> SGPRs
#pragma unroll
  for (int i = 0; i < QPW; i++) {
    int mq = n0 + j * QPW + i;
    float x = xb[mq], y = xb[N_ + mq], z = xb[2 * N_ + mq];
    float sq = __fadd_rn(__fadd_rn(__fmul_rn(x, x), __fmul_rn(y, y)), __fmul_rn(z, z));
    qX[i] = rf(x); qY[i] = rf(y); qZ[i] = rf(z); qS[i] = rf(sq);
  }
  float tauF[QPW]; int cntA[QPW];
#pragma unroll
  for (int i = 0; i < QPW; i++) { tauF[i] = INF; cntA[i] = 0; }
  __syncthreads();  // prmL written, skey region free

  auto process = [&](float cx, float cy, float cz, int base) {
    float cw = __fadd_rn(__fadd_rn(__fmul_rn(cx, cx), __fmul_rn(cy, cy)),
                         __fmul_rn(cz, cz));
    float dd[QPW];
#pragma unroll
    for (int i = 0; i < QPW; i++) {
      // ref rounding: dot fma-chain; (qs+cw) one rnd; fma(-2,dot,s) ==
      // rnd(s - 2*dot) == rnd(s - rnd(2*dot)) since 2*dot is exact.
      float dot = fmaf(cz, qZ[i], fmaf(cy, qY[i], __fmul_rn(cx, qX[i])));
      dd[i] = fmaf(-2.0f, dot, __fadd_rn(qS[i], cw));
    }
#pragma unroll
    for (int i = 0; i < QPW; i++) {
      bool mine = dd[i] < tauF[i];
      unsigned long long hit = __ballot((int)mine);
      if (hit) {
        unsigned* skQ = skey + (j * QPW + i) * BUFS;
        unsigned short* siQ = sidx + (j * QPW + i) * BUFS;
        int h = __popcll(hit);
        int rk = mbcnt64(hit);
        unsigned key = mapkey(dd[i]);
        unsigned short mm = (unsigned short)(base + lane);
        if (cntA[i] + h <= BUFS) {  // fast path
          if (mine) { skQ[cntA[i] + rk] = key; siQ[cntA[i] + rk] = mm; }
          cntA[i] += h;
          if (cntA[i] == BUFS) {
            tauF[i] = rf(select16(skQ, siQ, BUFS, nullptr));
            cntA[i] = KNN;
          }
        } else {  // overflow: write in rounds, compacting as needed
          unsigned long long rem = hit; bool mrem = mine;
          while (rem) {
            int freeS = BUFS - cntA[i];
            int hh = __popcll(rem);
            int rr = mbcnt64(rem);
            bool wn = mrem && (rr < freeS);
            if (wn) { skQ[cntA[i] + rr] = key; siQ[cntA[i] + rr] = mm; }
            cntA[i] += (hh < freeS) ? hh : freeS;
            if (cntA[i] == BUFS) {
              tauF[i] = rf(select16(skQ, siQ, BUFS, nullptr));
              cntA[i] = KNN;
            }
            mrem = mrem && !wn && (dd[i] < tauF[i]);
            rem = __ballot((int)mrem);
          }
        }
      }
    }
  };

  // depth-2 software pipeline over 64-candidate batches
  float x0 = xb[lane],      y0 = xb[N_ + lane],      z0 = xb[2 * N_ + lane];
  float x1 = xb[64 + lane], y1 = xb[N_ + 64 + lane], z1 = xb[2 * N_ + 64 + lane];
  for (int m0 = 0; m0 < N_; m0 += 64) {
    const int mn = (m0 + 128) & (N_ - 1);  // wrapped prefetch (always in-bounds)
    float x2 = xb[mn + lane], y2 = xb[N_ + mn + lane], z2 = xb[2 * N_ + mn + lane];
    process(x0, y0, z0, m0);
    x0 = x1; y0 = y1; z0 = z1;
    x1 = x2; y1 = y2; z1 = z2;
  }
  // final exact selection per query -> fidx[slot][query]
#pragma unroll
  for (int i = 0; i < QPW; i++) {
    select16(skey + (j * QPW + i) * BUFS, sidx + (j * QPW + i) * BUFS,
             cntA[i], fidx + (j * QPW + i));
  }
  __syncthreads();

  // ---- phase 2: epilogue.  thread = (q = t&15, g = t>>4, g<16) ----
  const int q = t & 15;
  const int g = t >> 4;
  const float qx = xb[n0 + q], qy = xb[N_ + n0 + q], qz = xb[2 * N_ + n0 + q];
  float* nb = (float*)poolRaw;             // neighbor rows [64][16] (over skey)
  float* feFe = (float*)(poolRaw + 8704);  // fe [64][16]
  {  // gather: thread handles neighbor slot k=g for query q
    int m = fidx[g * QPB + q];
    float x = xb[m], y = xb[N_ + m], z = xb[2 * N_ + m];
    float dx = __fsub_rn(x, qx), dy = __fsub_rn(y, qy), dz = __fsub_rn(z, qz);
    float dsq = __fadd_rn(__fadd_rn(__fmul_rn(dx, dx), __fmul_rn(dy, dy)),
                          __fmul_rn(dz, dz));
    nb[g * QPB + q] = x;
    nb[(16 + g) * QPB + q] = y;
    nb[(32 + g) * QPB + q] = z;
    nb[(48 + g) * QPB + q] = dsq;
  }
  __syncthreads();

  {  // fe: thread computes channels c = g*4..+3 for query q
    float mx0 = -INF, mx1 = -INF, mx2 = -INF, mx3 = -INF;
    const int c0 = g * 4;
    float4 pB0 = prmL[64 + c0], pB1 = prmL[64 + c0 + 1];
    float4 pB2 = prmL[64 + c0 + 2], pB3 = prmL[64 + c0 + 3];
#pragma unroll
    for (int k = 0; k < KNN; k++) {
      float nx = nb[k * QPB + q], ny = nb[(16 + k) * QPB + q];
      float nz = nb[(32 + k) * QPB + q], nd = nb[(48 + k) * QPB + q];
      mx0 = fmaxf(mx0, fmaf(nz, pB0.z, fmaf(ny, pB0.y, fmaf(nx, pB0.x, __fmul_rn(nd, pB0.w)))));
      mx1 = fmaxf(mx1, fmaf(nz, pB1.z, fmaf(ny, pB1.y, fmaf(nx, pB1.x, __fmul_rn(nd, pB1.w)))));
      mx2 = fmaxf(mx2, fmaf(nz, pB2.z, fmaf(ny, pB2.y, fmaf(nx, pB2.x, __fmul_rn(nd, pB2.w)))));
      mx3 = fmaxf(mx3, fmaf(nz, pB3.z, fmaf(ny, pB3.y, fmaf(nx, pB3.x, __fmul_rn(nd, pB3.w)))));
    }
    float4 pA0 = prmL[c0], pA1 = prmL[c0 + 1], pA2 = prmL[c0 + 2], pA3 = prmL[c0 + 3];
    feFe[(c0 + 0) * QPB + q] = fmaf(qz, pA0.z, fmaf(qy, pA0.y, fmaf(qx, pA0.x, pA0.w))) + mx0;
    feFe[(c0 + 1) * QPB + q] = fmaf(qz, pA1.z, fmaf(qy, pA1.y, fmaf(qx, pA1.x, pA1.w))) + mx1;
    feFe[(c0 + 2) * QPB + q] = fmaf(qz, pA2.z, fmaf(qy, pA2.y, fmaf(qx, pA2.x, pA2.w))) + mx2;
    feFe[(c0 + 3) * QPB + q] = fmaf(qz, pA3.z, fmaf(qy, pA3.y, fmaf(qx, pA3.x, pA3.w))) + mx3;
  }
  __syncthreads();  // nb dead -> reuse for feature tile

  float* feL = (float*)poolRaw;  // [64][16]
#pragma unroll
  for (int ci = 0; ci < 4; ci++) {
    int c = g * 4 + ci;
    feL[c * QPB + q] = feature[(size_t)(b * DIN + c) * N_ + n0 + q];
  }
  __syncthreads();

  // shortcut GEMM: thread computes outputs o = g*8..+7 for query q
  float acc[8];
#pragma unroll
  for (int oi = 0; oi < 8; oi++) acc[oi] = 0.f;
  const float4* wsRow = (const float4*)(wsM + (size_t)g * 8 * DIN);  // 8 rows
  for (int c4 = 0; c4 < DIN / 4; c4++) {
    float f0 = feL[(4 * c4 + 0) * QPB + q];
    float f1 = feL[(4 * c4 + 1) * QPB + q];
    float f2 = feL[(4 * c4 + 2) * QPB + q];
    float f3 = feL[(4 * c4 + 3) * QPB + q];
#pragma unroll
    for (int oi = 0; oi < 8; oi++) {
      float4 w = wsRow[oi * (DIN / 4) + c4];  // group-uniform, L1-resident
      acc[oi] = fmaf(w.x, f0, acc[oi]);
      acc[oi] = fmaf(w.y, f1, acc[oi]);
      acc[oi] = fmaf(w.z, f2, acc[oi]);
      acc[oi] = fmaf(w.w, f3, acc[oi]);
    }
  }
  float* ob = out + (size_t)b * DOUT * N_ + n0 + q;
#pragma unroll
  for (int oi = 0; oi < 8; oi++) {
    int o = g * 8 + oi;
    ob[(size_t)o * N_] = acc[oi] + bs[o] + feFe[(o & 63) * QPB + q];
  }
}

extern "C" void kernel_launch(void* const* d_in, const int* in_sizes, int n_in,
                              void* d_out, int out_size, void* d_ws, size_t ws_size,
                              hipStream_t stream) {
  const float* xyz     = (const float*)d_in[0];
  const float* feature = (const float*)d_in[1];
  const float* w1 = (const float*)d_in[2];
  const float* b1 = (const float*)d_in[3];
  const float* w2 = (const float*)d_in[4];
  const float* b2 = (const float*)d_in[5];
  const float* w3 = (const float*)d_in[6];
  const float* b3 = (const float*)d_in[7];
  const float* wsM = (const float*)d_in[8];
  const float* bs  = (const float*)d_in[9];
  float* out = (float*)d_out;

  hipLaunchKernelGGL(k_lfa, dim3(B_ * BLOCKS_PER_B), dim3(NTHR), 0, stream,
                     xyz, feature, w1, b1, w2, b2, w3, b3, wsM, bs, out);
}